// Round 2
// baseline (135.119 us; speedup 1.0000x reference)
//
#include <hip/hip_runtime.h>

// EmbeddingBag sum: out[b, :] = sum_{j<BAG} weight[input[b,j], :]
// input: int32 [BATCH, BAG], weight: fp32 [NUM_EMB+1, EMB_DIM], out: fp32 [BATCH, EMB_DIM]

constexpr int BATCH = 16384;
constexpr int BAG = 50;
constexpr int DIM = 128;                 // 32 float4 per row
constexpr int LANES_PER_ROW = 32;        // each lane owns one float4
constexpr int ROWS_PER_BLOCK = 8;        // 256 threads / 32 lanes
constexpr int BLOCK = LANES_PER_ROW * ROWS_PER_BLOCK;

__global__ __launch_bounds__(BLOCK) void embbag_sum_kernel(
    const int* __restrict__ idx,
    const float* __restrict__ weight,
    float* __restrict__ out) {
    const int lane = threadIdx.x & (LANES_PER_ROW - 1);
    const int rowInBlock = threadIdx.x >> 5;
    const int row = blockIdx.x * ROWS_PER_BLOCK + rowInBlock;
    if (row >= BATCH) return;

    const int* __restrict__ ip = idx + (size_t)row * BAG;

    float4 acc = make_float4(0.f, 0.f, 0.f, 0.f);

#pragma unroll 5
    for (int j = 0; j < BAG; ++j) {
        const int id = ip[j];
        const float4 v =
            reinterpret_cast<const float4*>(weight + (size_t)id * DIM)[lane];
        acc.x += v.x;
        acc.y += v.y;
        acc.z += v.z;
        acc.w += v.w;
    }

    reinterpret_cast<float4*>(out + (size_t)row * DIM)[lane] = acc;
}

extern "C" void kernel_launch(void* const* d_in, const int* in_sizes, int n_in,
                              void* d_out, int out_size, void* d_ws, size_t ws_size,
                              hipStream_t stream) {
    const int* idx = (const int*)d_in[0];        // [BATCH, BAG] int32
    const float* weight = (const float*)d_in[1]; // [NUM_EMB+1, DIM] fp32
    float* out = (float*)d_out;                  // [BATCH, DIM] fp32

    const int grid = BATCH / ROWS_PER_BLOCK;     // 2048 blocks
    embbag_sum_kernel<<<grid, BLOCK, 0, stream>>>(idx, weight, out);
}

// Round 3
// 131.092 us; speedup vs baseline: 1.0307x; 1.0307x over previous
//
#include <hip/hip_runtime.h>

// EmbeddingBag sum: out[b, :] = sum_{j<BAG} weight[input[b,j], :]
// input: int32 [BATCH, BAG], weight: fp32 [NUM_EMB+1, EMB_DIM], out: fp32 [BATCH, EMB_DIM]
//
// Structure: one output row per 64-lane wave; lane holds float2 (64*8B = 512B row).
// Row index made wave-uniform via readfirstlane so the 50 bag indices compile to
// scalar s_loads (SGPRs), leaving VGPRs free for deep gather pipelining (MLP).

constexpr int BATCH = 16384;
constexpr int BAG = 50;
constexpr int DIM = 128;
constexpr int WAVES_PER_BLOCK = 4;
constexpr int BLOCK = 64 * WAVES_PER_BLOCK;

__global__ __launch_bounds__(BLOCK) void embbag_sum_kernel(
    const int* __restrict__ idx,
    const float* __restrict__ weight,
    float* __restrict__ out) {
    const int lane = threadIdx.x & 63;
    // wave-uniform row id in an SGPR -> index loads become scalar loads
    const int row = __builtin_amdgcn_readfirstlane(
        blockIdx.x * WAVES_PER_BLOCK + (threadIdx.x >> 6));

    const int* __restrict__ ip = idx + (size_t)row * BAG;

    // Preload all 50 bag indices (uniform address -> s_load_dwordx16 merges)
    int ids[BAG];
#pragma unroll
    for (int j = 0; j < BAG; ++j) ids[j] = ip[j];

    float2 acc = make_float2(0.f, 0.f);

    // Fully unrolled gather-accumulate: each gather costs only 2 VGPRs in flight,
    // scalar base address (id is SGPR) + per-lane voffset -> deep MLP.
#pragma unroll
    for (int j = 0; j < BAG; ++j) {
        const float2 v = *reinterpret_cast<const float2*>(
            weight + (size_t)ids[j] * DIM + lane * 2);
        acc.x += v.x;
        acc.y += v.y;
    }

    *reinterpret_cast<float2*>(out + (size_t)row * DIM + lane * 2) = acc;
}

extern "C" void kernel_launch(void* const* d_in, const int* in_sizes, int n_in,
                              void* d_out, int out_size, void* d_ws, size_t ws_size,
                              hipStream_t stream) {
    const int* idx = (const int*)d_in[0];        // [BATCH, BAG] int32
    const float* weight = (const float*)d_in[1]; // [NUM_EMB+1, DIM] fp32
    float* out = (float*)d_out;                  // [BATCH, DIM] fp32

    const int grid = BATCH / WAVES_PER_BLOCK;    // 4096 blocks
    embbag_sum_kernel<<<grid, BLOCK, 0, stream>>>(idx, weight, out);
}

// Round 5
// 130.785 us; speedup vs baseline: 1.0331x; 1.0023x over previous
//
#include <hip/hip_runtime.h>

// EmbeddingBag sum: out[b, :] = sum_{j<BAG} weight[input[b,j], :]
// input: int32 [BATCH, BAG], weight: fp32 [NUM_EMB+1, EMB_DIM], out: fp32 [BATCH, EMB_DIM]
//
// MLP probe: one row per 64-lane wave (lane holds float2 = 512B/row).
// All 50 gathers are issued into a statically-indexed register array BEFORE
// any accumulation -> ~50 outstanding vmem ops per wave (~25KB in flight/wave).
// launch_bounds(256,2) lifts VGPR cap to 256 so the 100-VGPR payload doesn't spill.
// Wave-uniform row id -> 50 bag indices live in SGPRs (s_load_dwordx16).

constexpr int BATCH = 16384;
constexpr int BAG = 50;
constexpr int DIM = 128;
constexpr int WAVES_PER_BLOCK = 4;
constexpr int BLOCK = 64 * WAVES_PER_BLOCK;

__global__ __launch_bounds__(BLOCK, 2) void embbag_sum_kernel(
    const int* __restrict__ idx,
    const float* __restrict__ weight,
    float* __restrict__ out) {
    const int lane = threadIdx.x & 63;
    const int row = __builtin_amdgcn_readfirstlane(
        blockIdx.x * WAVES_PER_BLOCK + (threadIdx.x >> 6));

    const int* __restrict__ ip = idx + (size_t)row * BAG;

    // Wave-uniform -> scalar loads into SGPRs
    int ids[BAG];
#pragma unroll
    for (int j = 0; j < BAG; ++j) ids[j] = ip[j];

    // Issue ALL 50 gathers first (static indexing keeps v[] in VGPRs)
    float2 v[BAG];
#pragma unroll
    for (int j = 0; j < BAG; ++j) {
        v[j] = *reinterpret_cast<const float2*>(
            weight + (size_t)ids[j] * DIM + lane * 2);
    }

    // Then reduce
    float2 acc = make_float2(0.f, 0.f);
#pragma unroll
    for (int j = 0; j < BAG; ++j) {
        acc.x += v[j].x;
        acc.y += v[j].y;
    }

    *reinterpret_cast<float2*>(out + (size_t)row * DIM + lane * 2) = acc;
}

extern "C" void kernel_launch(void* const* d_in, const int* in_sizes, int n_in,
                              void* d_out, int out_size, void* d_ws, size_t ws_size,
                              hipStream_t stream) {
    const int* idx = (const int*)d_in[0];        // [BATCH, BAG] int32
    const float* weight = (const float*)d_in[1]; // [NUM_EMB+1, DIM] fp32
    float* out = (float*)d_out;                  // [BATCH, DIM] fp32

    const int grid = BATCH / WAVES_PER_BLOCK;    // 4096 blocks
    embbag_sum_kernel<<<grid, BLOCK, 0, stream>>>(idx, weight, out);
}